// Round 1
// baseline (249.778 us; speedup 1.0000x reference)
//
#include <hip/hip_runtime.h>
#include <cstdint>

typedef unsigned short u16;
typedef __bf16 bf16x8 __attribute__((ext_vector_type(8)));
typedef float f32x4 __attribute__((ext_vector_type(4)));
typedef short s4 __attribute__((ext_vector_type(4)));

#define T_SEQ 2048
#define NH 16

// RTNE float -> bf16 bits
__device__ __forceinline__ u16 f2bf(float f) {
  union { float f; uint32_t u; } x; x.f = f;
  uint32_t r = (x.u + 0x7fffu + ((x.u >> 16) & 1u)) >> 16;
  return (u16)r;
}

// pack two floats -> two bf16 (RTNE)
__device__ __forceinline__ uint32_t pk2bf(float a, float b) {
  union { float f; uint32_t u; } x, y; x.f = a; y.f = b;
  uint32_t lo = (x.u + 0x7fffu + ((x.u >> 16) & 1u)) >> 16;
  uint32_t hi = (y.u + 0x7fffu + ((y.u >> 16) & 1u)) >> 16;
  return lo | (hi << 16);
}

// 8 fp32 -> 8 bf16 (one uint4 store)
__device__ __forceinline__ void cvt8(u16* dst, const float* src) {
  float4 a = *(const float4*)src;
  float4 b = *(const float4*)(src + 4);
  uint4 o;
  o.x = pk2bf(a.x, a.y); o.y = pk2bf(a.z, a.w);
  o.z = pk2bf(b.x, b.y); o.w = pk2bf(b.z, b.w);
  *(uint4*)dst = o;
}

// grid-stride fp32 -> bf16, 8 elems/thread
__global__ __launch_bounds__(256) void cvt_f32_bf16(const float* __restrict__ src,
                                                    u16* __restrict__ dst, int n8) {
  int i = blockIdx.x * 256 + threadIdx.x;
  if (i < n8) cvt8(&dst[(size_t)i * 8], &src[(size_t)i * 8]);
}

// f32x4 accumulator quad -> 4 bf16 (RTNE via hw cvt)
__device__ __forceinline__ s4 cvt4(f32x4 v) {
  union { __bf16 b[4]; s4 s; } u;
  u.b[0] = (__bf16)v[0]; u.b[1] = (__bf16)v[1];
  u.b[2] = (__bf16)v[2]; u.b[3] = (__bf16)v[3];
  return u.s;
}

__device__ __forceinline__ f32x4 mfma16(s4 a, s4 b, f32x4 c) {
#if __has_builtin(__builtin_amdgcn_mfma_f32_16x16x16bf16_1k)
  return __builtin_amdgcn_mfma_f32_16x16x16bf16_1k(a, b, c, 0, 0, 0);
#else
  asm("v_mfma_f32_16x16x16_bf16 %0, %1, %2, %0" : "+v"(c) : "v"(a), "v"(b));
  return c;
#endif
}

// C[M,N] = A[M,K] * W[N,K]^T. A,W bf16; C fp32 (CF32) or bf16 ws.
// KV: blocks with cols>=1024 additionally write fp32 k/v outputs.
// tile BMx128, BK=64, 256 threads = 4 waves 2x2, each wave (BM/2)x64
template <bool CF32, bool KV, int BM>
__global__ __launch_bounds__(256) void gemm_bt(
    const u16* __restrict__ A, const u16* __restrict__ W,
    void* __restrict__ Cp, float* __restrict__ outk, float* __restrict__ outv,
    int M, int N, int K) {
  constexpr int MI = BM / 32;
  __shared__ __align__(16) u16 As[BM * 72];
  __shared__ __align__(16) u16 Bs[128 * 72];
  const int tid  = threadIdx.x;
  const int n0   = blockIdx.x * 128;
  const int m0   = blockIdx.y * BM;
  const int lane = tid & 63;
  const int wave = tid >> 6;
  const int wm   = (wave >> 1) * (BM / 2);
  const int wn   = (wave & 1) * 64;
  const int l15  = lane & 15;
  const int quad = lane >> 4;
  const int t8   = tid & 7;
  const int rowb = tid >> 3;

  f32x4 acc[MI][4];
#pragma unroll
  for (int i = 0; i < MI; i++)
#pragma unroll
    for (int j = 0; j < 4; j++) acc[i][j] = (f32x4){0.f, 0.f, 0.f, 0.f};

  for (int k0 = 0; k0 < K; k0 += 64) {
    __syncthreads();
#pragma unroll
    for (int r = 0; r < 4; r++) {
      int row = rowb + r * 32;
      if (r < MI)
        *(uint4*)&As[row * 72 + t8 * 8] =
            *(const uint4*)&A[(size_t)(m0 + row) * K + k0 + t8 * 8];
      *(uint4*)&Bs[row * 72 + t8 * 8] =
          *(const uint4*)&W[(size_t)(n0 + row) * K + k0 + t8 * 8];
    }
    __syncthreads();
#pragma unroll
    for (int kk = 0; kk < 64; kk += 32) {
      bf16x8 af[MI], bfr[4];
#pragma unroll
      for (int i = 0; i < MI; i++)
        af[i] = *(const bf16x8*)&As[(wm + i * 16 + l15) * 72 + kk + quad * 8];
#pragma unroll
      for (int j = 0; j < 4; j++)
        bfr[j] = *(const bf16x8*)&Bs[(wn + j * 16 + l15) * 72 + kk + quad * 8];
#pragma unroll
      for (int i = 0; i < MI; i++)
#pragma unroll
        for (int j = 0; j < 4; j++)
          acc[i][j] = __builtin_amdgcn_mfma_f32_16x16x32_bf16(af[i], bfr[j], acc[i][j], 0, 0, 0);
    }
  }
#pragma unroll
  for (int i = 0; i < MI; i++)
#pragma unroll
    for (int j = 0; j < 4; j++)
#pragma unroll
      for (int r = 0; r < 4; r++) {
        int row = m0 + wm + i * 16 + quad * 4 + r;
        int col = n0 + wn + j * 16 + l15;
        float v = acc[i][j][r];
        if constexpr (CF32) {
          ((float*)Cp)[(size_t)row * N + col] = v;
        } else {
          ((u16*)Cp)[(size_t)row * N + col] = f2bf(v);
          if constexpr (KV) {
            if (col >= 2048)      outv[(size_t)row * 1024 + (col - 2048)] = v;
            else if (col >= 1024) outk[(size_t)row * 1024 + (col - 1024)] = v;
          }
        }
      }
}

// vt[(b*NH+h)*64 + d][t] = v[b,t,h,d]   (64x64 LDS tile transpose, bf16 ws)
__global__ __launch_bounds__(256) void transpose_v(const u16* __restrict__ qkv,
                                                   u16* __restrict__ vt) {
  __shared__ __align__(16) u16 tile[64 * 72];
  int t0 = blockIdx.x * 64;
  int bh = blockIdx.y;
  int b = bh >> 4, h = bh & 15;
  int tid = threadIdx.x;
  int t8 = tid & 7, rowb = tid >> 3;
#pragma unroll
  for (int r = 0; r < 2; r++) {
    int row = rowb + r * 32;
    *(uint4*)&tile[row * 72 + t8 * 8] =
        *(const uint4*)&qkv[((size_t)b * T_SEQ + t0 + row) * 3072 + 2048 + h * 64 + t8 * 8];
  }
  __syncthreads();
#pragma unroll
  for (int r = 0; r < 2; r++) {
    int d = rowb + r * 32;
    union { u16 s[8]; uint4 u; } tmp;
#pragma unroll
    for (int e = 0; e < 8; e++) tmp.s[e] = tile[(t8 * 8 + e) * 72 + d];
    *(uint4*)&vt[((size_t)(b * NH + h) * 64 + d) * 2048 + t0 + t8 * 8] = tmp.u;
  }
}

// Flash-style causal attention with SWAPPED QK^T (S^T = mfma(K,Q)):
// each lane owns one q-row (q = wq0+l15) and k = j*16+quad*4+r, so
//  - softmax max/sum: 15 lane-local ops + 2 shfl_xor (16,32)
//  - P feeds PV directly from registers as the 16x16x16 A-operand
//    (k = quad*4+e) -- no P LDS round-trip, no fence barrier.
// Q-frags are k-invariant -> loaded once from global, no Qs LDS.
// Grid: 1024 blocks (one 64-row q-tile each), qt=(bx+by)&31 mixes sizes.
__global__ __launch_bounds__(256) void attn(const u16* __restrict__ qkv,
                                            const u16* __restrict__ vt,
                                            u16* __restrict__ o) {
  __shared__ __align__(16) u16 Ks[64 * 72];
  __shared__ __align__(16) u16 Vts[64 * 72];

  const int tid  = threadIdx.x;
  const int qt   = (int)((blockIdx.x + blockIdx.y) & 31);
  const int bh   = blockIdx.y;
  const int b    = bh >> 4, h = bh & 15;
  const int lane = tid & 63, wave = tid >> 6;
  const int l15  = lane & 15, quad = lane >> 4;
  const int t8   = tid & 7, rowb = tid >> 3;
  const size_t qbase = (size_t)b * T_SEQ * 3072;
  const size_t vbase = (size_t)(b * NH + h) * 64 * 2048;
  const int q0   = qt * 64;
  const int wq0  = q0 + wave * 16;
  const int qrow = wq0 + l15;  // this lane's q-row

  // Q fragments (B-operand layout: n=l15 -> q, k-dim = quad*8+e), from global
  const u16* qp = &qkv[qbase + (size_t)qrow * 3072 + h * 64];
  const bf16x8 qf0 = *(const bf16x8*)&qp[quad * 8];
  const bf16x8 qf1 = *(const bf16x8*)&qp[32 + quad * 8];

  f32x4 acc_o[4];
#pragma unroll
  for (int n = 0; n < 4; n++) acc_o[n] = (f32x4){0.f, 0.f, 0.f, 0.f};
  float mrun = -1e30f, lrun = 0.f;

  for (int kt = 0; kt <= qt; kt++) {
    const int k0 = kt * 64;
    __syncthreads();
#pragma unroll
    for (int r = 0; r < 2; r++) {
      int row = rowb + r * 32;
      *(uint4*)&Ks[row * 72 + t8 * 8] =
          *(const uint4*)&qkv[qbase + (size_t)(k0 + row) * 3072 + 1024 + h * 64 + t8 * 8];
      *(uint4*)&Vts[row * 72 + t8 * 8] =
          *(const uint4*)&vt[vbase + (size_t)row * 2048 + k0 + t8 * 8];
    }
    __syncthreads();

    // S^T[j]: row (quad*4+r) = k_local, col l15 = q
    f32x4 sacc[4];
#pragma unroll
    for (int j = 0; j < 4; j++) sacc[j] = (f32x4){0.f, 0.f, 0.f, 0.f};
#pragma unroll
    for (int j = 0; j < 4; j++) {
      bf16x8 kf = *(const bf16x8*)&Ks[(j * 16 + l15) * 72 + quad * 8];
      sacc[j] = __builtin_amdgcn_mfma_f32_16x16x32_bf16(kf, qf0, sacc[j], 0, 0, 0);
    }
#pragma unroll
    for (int j = 0; j < 4; j++) {
      bf16x8 kf = *(const bf16x8*)&Ks[(j * 16 + l15) * 72 + 32 + quad * 8];
      sacc[j] = __builtin_amdgcn_mfma_f32_16x16x32_bf16(kf, qf1, sacc[j], 0, 0, 0);
    }

    if (kt == qt) {
#pragma unroll
      for (int j = 0; j < 4; j++)
#pragma unroll
        for (int r = 0; r < 4; r++) {
          int k = k0 + j * 16 + quad * 4 + r;
          sacc[j][r] = (k > qrow) ? -1e30f : sacc[j][r] * 0.125f;
        }
    } else {
#pragma unroll
      for (int j = 0; j < 4; j++)
#pragma unroll
        for (int r = 0; r < 4; r++) sacc[j][r] *= 0.125f;
    }

    // online softmax: lane-local over 16 vals + cross-quad (2 shfl each)
    float mx = sacc[0][0];
#pragma unroll
    for (int j = 0; j < 4; j++)
#pragma unroll
      for (int r = 0; r < 4; r++) mx = fmaxf(mx, sacc[j][r]);
    mx = fmaxf(mx, __shfl_xor(mx, 16));
    mx = fmaxf(mx, __shfl_xor(mx, 32));
    const float mnew  = fmaxf(mrun, mx);
    const float alpha = __expf(mrun - mnew);
    float sum = 0.f;
#pragma unroll
    for (int j = 0; j < 4; j++)
#pragma unroll
      for (int r = 0; r < 4; r++) {
        float p = __expf(sacc[j][r] - mnew);
        sacc[j][r] = p;
        sum += p;
      }
    sum += __shfl_xor(sum, 16);
    sum += __shfl_xor(sum, 32);
    lrun = lrun * alpha + sum;
    mrun = mnew;

    // rescale O rows: alpha lives at lane l15 = quad*4+r
#pragma unroll
    for (int r = 0; r < 4; r++) {
      float ar = __shfl(alpha, quad * 4 + r);
#pragma unroll
      for (int n = 0; n < 4; n++) acc_o[n][r] *= ar;
    }

    // P -> bf16 A-frags for 16x16x16 (m=l15 -> q, k = quad*4+e) : in-register
    s4 pa[4];
#pragma unroll
    for (int j = 0; j < 4; j++) pa[j] = cvt4(sacc[j]);

    // PV: B-frag = V^T[d = n*16+l15][k = j*16+quad*4 ..+3] (ds_read_b64)
#pragma unroll
    for (int j = 0; j < 4; j++)
#pragma unroll
      for (int n = 0; n < 4; n++) {
        s4 vf = *(const s4*)&Vts[(n * 16 + l15) * 72 + j * 16 + quad * 4];
        acc_o[n] = mfma16(pa[j], vf, acc_o[n]);
      }
  }

  const float linv = 1.0f / lrun;
#pragma unroll
  for (int r = 0; r < 4; r++) {
    const float lr = __shfl(linv, quad * 4 + r);
    const int row = wq0 + quad * 4 + r;
#pragma unroll
    for (int n = 0; n < 4; n++)
      o[(size_t)(b * T_SEQ + row) * 1024 + h * 64 + n * 16 + l15] =
          f2bf(acc_o[n][r] * lr);
  }
}

extern "C" void kernel_launch(void* const* d_in, const int* in_sizes, int n_in,
                              void* d_out, int out_size, void* d_ws, size_t ws_size,
                              hipStream_t stream) {
  const float* x     = (const float*)d_in[0];   // (2,2048,1024) fp32
  const float* w_qkv = (const float*)d_in[1];   // (3072,1024)   fp32
  const float* w_o   = (const float*)d_in[2];   // (1024,1024)   fp32
  float* out  = (float*)d_out;                  // fp32 (4096,1024)
  float* outk = out + (size_t)4194304;
  float* outv = out + (size_t)8388608;

  u16* qkv = (u16*)d_ws;                        // 4096*3072
  u16* vt  = qkv + (size_t)4096 * 3072;         // 32*64*2048
  u16* ao  = vt  + (size_t)4194304;             // 4096*1024
  u16* xb  = ao  + (size_t)4194304;             // 4096*1024
  u16* wqb = xb  + (size_t)4194304;             // 3072*1024
  u16* wob = wqb + (size_t)3145728;             // 1024*1024

  // 0. one-time fp32 -> bf16 conversion of inputs
  cvt_f32_bf16<<<2048, 256, 0, stream>>>(x, xb, 524288);
  cvt_f32_bf16<<<1536, 256, 0, stream>>>(w_qkv, wqb, 393216);
  cvt_f32_bf16<<<512, 256, 0, stream>>>(w_o, wob, 131072);

  // 1. qkv(bf16 ws) = xb @ wqb^T; k/v cols also -> fp32 outputs
  gemm_bt<false, true, 128><<<dim3(24, 32), 256, 0, stream>>>(
      xb, wqb, qkv, outk, outv, 4096, 3072, 1024);
  // 2. v -> v^T ws
  transpose_v<<<dim3(32, 32), 256, 0, stream>>>(qkv, vt);
  // 3. flash attention -> ao (bf16 ws)
  attn<<<dim3(32, 32), 256, 0, stream>>>(qkv, vt, ao);
  // 4. out(fp32) = ao @ wob^T  (BM=64 -> 512 blocks, was 256 = 1/CU)
  gemm_bt<true, false, 64><<<dim3(8, 64), 256, 0, stream>>>(
      ao, wob, out, nullptr, nullptr, 4096, 1024, 1024);
}

// Round 2
// 214.531 us; speedup vs baseline: 1.1643x; 1.1643x over previous
//
#include <hip/hip_runtime.h>
#include <cstdint>

typedef unsigned short u16;
typedef __bf16 bf16x8 __attribute__((ext_vector_type(8)));
typedef float f32x4 __attribute__((ext_vector_type(4)));
typedef short s4 __attribute__((ext_vector_type(4)));

#define T_SEQ 2048
#define NH 16

// RTNE float -> bf16 bits
__device__ __forceinline__ u16 f2bf(float f) {
  union { float f; uint32_t u; } x; x.f = f;
  uint32_t r = (x.u + 0x7fffu + ((x.u >> 16) & 1u)) >> 16;
  return (u16)r;
}

// pack two floats -> two bf16 (RTNE)
__device__ __forceinline__ uint32_t pk2bf(float a, float b) {
  union { float f; uint32_t u; } x, y; x.f = a; y.f = b;
  uint32_t lo = (x.u + 0x7fffu + ((x.u >> 16) & 1u)) >> 16;
  uint32_t hi = (y.u + 0x7fffu + ((y.u >> 16) & 1u)) >> 16;
  return lo | (hi << 16);
}

// 8 fp32 -> 8 bf16 (one uint4 store)
__device__ __forceinline__ void cvt8(u16* dst, const float* src) {
  float4 a = *(const float4*)src;
  float4 b = *(const float4*)(src + 4);
  uint4 o;
  o.x = pk2bf(a.x, a.y); o.y = pk2bf(a.z, a.w);
  o.z = pk2bf(b.x, b.y); o.w = pk2bf(b.z, b.w);
  *(uint4*)dst = o;
}

// fused fp32 -> bf16 conversion of x, w_qkv, w_o (dst regions contiguous in ws)
// 8-elem units: x [0,524288), w_qkv [524288,917504), w_o [917504,1048576)
__global__ __launch_bounds__(256) void cvt_all(const float* __restrict__ x,
                                               const float* __restrict__ wq,
                                               const float* __restrict__ wo,
                                               u16* __restrict__ dst) {
  int i = blockIdx.x * 256 + threadIdx.x;
  const float* src; int off;
  if (i < 524288)      { src = x;  off = 0; }
  else if (i < 917504) { src = wq; off = 524288; }
  else                 { src = wo; off = 917504; }
  cvt8(&dst[(size_t)i * 8], &src[(size_t)(i - off) * 8]);
}

// f32x4 accumulator quad -> 4 bf16 (RTNE via hw cvt)
__device__ __forceinline__ s4 cvt4(f32x4 v) {
  union { __bf16 b[4]; s4 s; } u;
  u.b[0] = (__bf16)v[0]; u.b[1] = (__bf16)v[1];
  u.b[2] = (__bf16)v[2]; u.b[3] = (__bf16)v[3];
  return u.s;
}

__device__ __forceinline__ f32x4 mfma16(s4 a, s4 b, f32x4 c) {
#if __has_builtin(__builtin_amdgcn_mfma_f32_16x16x16bf16_1k)
  return __builtin_amdgcn_mfma_f32_16x16x16bf16_1k(a, b, c, 0, 0, 0);
#else
  asm("v_mfma_f32_16x16x16_bf16 %0, %1, %2, %0" : "+v"(c) : "v"(a), "v"(b));
  return c;
#endif
}

// async 16B global -> LDS (HW scatters lane i at ldsbase + i*16)
__device__ __forceinline__ void gl_lds(const u16* g, u16* ldsbase) {
  __builtin_amdgcn_global_load_lds(
      (const __attribute__((address_space(1))) void*)g,
      (__attribute__((address_space(3))) void*)ldsbase, 16, 0, 0);
}

// C[M,N] = A[M,K] * W[N,K]^T. A,W bf16; C fp32 (CF32) or bf16 ws.
// KV: cols>=1024 additionally write fp32 k/v outputs.
// tile 128x128, BK=64, global_load_lds staging, XOR-swizzled linear LDS:
//   LDS[row][chunk c] = G[row][chunk c ^ (row&7)]  (chunk = 16B)
template <bool CF32, bool KV>
__global__ __launch_bounds__(256) void gemm_bt(
    const u16* __restrict__ A, const u16* __restrict__ W,
    void* __restrict__ Cp, float* __restrict__ outk, float* __restrict__ outv,
    int M, int N, int K) {
  __shared__ __align__(16) u16 As[128 * 64];
  __shared__ __align__(16) u16 Bs[128 * 64];
  const int tid  = threadIdx.x;
  const int n0   = blockIdx.x * 128;
  const int m0   = blockIdx.y * 128;
  const int lane = tid & 63;
  const int wave = tid >> 6;
  const int wm   = (wave >> 1) * 64;
  const int wn   = (wave & 1) * 64;
  const int l15  = lane & 15;
  const int quad = lane >> 4;
  const int srow = lane >> 3;   // row within 8-row stage group
  const int sc   = lane & 7;    // 16B chunk within row

  f32x4 acc[4][4];
#pragma unroll
  for (int i = 0; i < 4; i++)
#pragma unroll
    for (int j = 0; j < 4; j++) acc[i][j] = (f32x4){0.f, 0.f, 0.f, 0.f};

  for (int k0 = 0; k0 < K; k0 += 64) {
    __syncthreads();  // all waves done reading As/Bs from previous step
#pragma unroll
    for (int i = 0; i < 4; i++) {
      int r0  = (i * 4 + wave) * 8;
      int row = r0 + srow;
      int gc  = (sc ^ (row & 7)) << 3;  // pre-swizzled source column (u16)
      gl_lds(&A[(size_t)(m0 + row) * K + k0 + gc], &As[r0 * 64]);
      gl_lds(&W[(size_t)(n0 + row) * K + k0 + gc], &Bs[r0 * 64]);
    }
    __syncthreads();  // vmcnt(0) drain -> tile ready
#pragma unroll
    for (int kk = 0; kk < 64; kk += 32) {
      bf16x8 af[4], bfr[4];
#pragma unroll
      for (int i = 0; i < 4; i++) {
        int arow = wm + i * 16 + l15;
        af[i] = *(const bf16x8*)((const char*)As + arow * 128 +
                                 ((((kk >> 3) + quad) ^ (arow & 7)) << 4));
      }
#pragma unroll
      for (int j = 0; j < 4; j++) {
        int brow = wn + j * 16 + l15;
        bfr[j] = *(const bf16x8*)((const char*)Bs + brow * 128 +
                                  ((((kk >> 3) + quad) ^ (brow & 7)) << 4));
      }
#pragma unroll
      for (int i = 0; i < 4; i++)
#pragma unroll
        for (int j = 0; j < 4; j++)
          acc[i][j] = __builtin_amdgcn_mfma_f32_16x16x32_bf16(af[i], bfr[j], acc[i][j], 0, 0, 0);
    }
  }
#pragma unroll
  for (int i = 0; i < 4; i++)
#pragma unroll
    for (int j = 0; j < 4; j++)
#pragma unroll
      for (int r = 0; r < 4; r++) {
        int row = m0 + wm + i * 16 + quad * 4 + r;
        int col = n0 + wn + j * 16 + l15;
        float v = acc[i][j][r];
        if constexpr (CF32) {
          ((float*)Cp)[(size_t)row * N + col] = v;
        } else {
          ((u16*)Cp)[(size_t)row * N + col] = f2bf(v);
          if constexpr (KV) {
            if (col >= 2048)      outv[(size_t)row * 1024 + (col - 2048)] = v;
            else if (col >= 1024) outk[(size_t)row * 1024 + (col - 1024)] = v;
          }
        }
      }
}

// vt[(b*NH+h)*64 + d][t] = v[b,t,h,d]   (64x64 LDS tile transpose, bf16 ws)
__global__ __launch_bounds__(256) void transpose_v(const u16* __restrict__ qkv,
                                                   u16* __restrict__ vt) {
  __shared__ __align__(16) u16 tile[64 * 72];
  int t0 = blockIdx.x * 64;
  int bh = blockIdx.y;
  int b = bh >> 4, h = bh & 15;
  int tid = threadIdx.x;
  int t8 = tid & 7, rowb = tid >> 3;
#pragma unroll
  for (int r = 0; r < 2; r++) {
    int row = rowb + r * 32;
    *(uint4*)&tile[row * 72 + t8 * 8] =
        *(const uint4*)&qkv[((size_t)b * T_SEQ + t0 + row) * 3072 + 2048 + h * 64 + t8 * 8];
  }
  __syncthreads();
#pragma unroll
  for (int r = 0; r < 2; r++) {
    int d = rowb + r * 32;
    union { u16 s[8]; uint4 u; } tmp;
#pragma unroll
    for (int e = 0; e < 8; e++) tmp.s[e] = tile[(t8 * 8 + e) * 72 + d];
    *(uint4*)&vt[((size_t)(b * NH + h) * 64 + d) * 2048 + t0 + t8 * 8] = tmp.u;
  }
}

// Flash-style causal attention, swapped QK^T (S^T = mfma(K,Q)), paired q-tiles
// (pair, 31-pair) -> uniform 33 k-tile steps per block.  K/V double-buffered
// via global_load_lds (XOR-swizzled source, linear LDS, swizzled reads):
// per step: barrier -> issue async stage of next tile into buf^1 -> compute buf.
__global__ __launch_bounds__(256) void attn(const u16* __restrict__ qkv,
                                            const u16* __restrict__ vt,
                                            u16* __restrict__ o) {
  __shared__ __align__(16) u16 Ks[2][64 * 64];
  __shared__ __align__(16) u16 Vts[2][64 * 64];

  const int tid  = threadIdx.x;
  const int pair = blockIdx.x;          // 0..15 -> q-tiles (pair, 31-pair)
  const int bh   = blockIdx.y;
  const int b    = bh >> 4, h = bh & 15;
  const int lane = tid & 63, wave = tid >> 6;
  const int l15  = lane & 15, quad = lane >> 4;
  const int srow = lane >> 3, sc = lane & 7;
  const size_t qbase = (size_t)b * T_SEQ * 3072;
  const size_t vbase = (size_t)(b * NH + h) * 64 * 2048;

  // Q fragments for BOTH tiles, loaded once (B-operand: n=l15 -> q row)
  const int qtA = pair, qtB = 31 - pair;
  const int wq0A = qtA * 64 + wave * 16;
  const int wq0B = qtB * 64 + wave * 16;
  const u16* qpA = &qkv[qbase + (size_t)(wq0A + l15) * 3072 + h * 64];
  const u16* qpB = &qkv[qbase + (size_t)(wq0B + l15) * 3072 + h * 64];
  bf16x8 qf0 = *(const bf16x8*)&qpA[quad * 8];
  bf16x8 qf1 = *(const bf16x8*)&qpA[32 + quad * 8];
  const bf16x8 qB0 = *(const bf16x8*)&qpB[quad * 8];
  const bf16x8 qB1 = *(const bf16x8*)&qpB[32 + quad * 8];

  int qt = qtA, wq0 = wq0A, qrow = wq0A + l15;

  f32x4 acc_o[4];
#pragma unroll
  for (int n = 0; n < 4; n++) acc_o[n] = (f32x4){0.f, 0.f, 0.f, 0.f};
  float mrun = -1e30f, lrun = 0.f;

  // async stage of k-tile (k0) into buffer d: 2 issues/array/wave, 8 rows each
  auto stage = [&](int d, int k0) {
#pragma unroll
    for (int i = 0; i < 2; i++) {
      int r0  = (wave * 2 + i) * 8;
      int row = r0 + srow;
      int gc  = (sc ^ (row & 7)) << 3;
      gl_lds(&qkv[qbase + (size_t)(k0 + row) * 3072 + 1024 + h * 64 + gc], &Ks[d][r0 * 64]);
      gl_lds(&vt[vbase + (size_t)row * 2048 + k0 + gc], &Vts[d][r0 * 64]);
    }
  };

  auto writeout = [&]() {
    float linv = 1.0f / lrun;
#pragma unroll
    for (int r = 0; r < 4; r++) {
      float lr = __shfl(linv, quad * 4 + r);
      int row = wq0 + quad * 4 + r;
#pragma unroll
      for (int n = 0; n < 4; n++)
        o[(size_t)(b * T_SEQ + row) * 1024 + h * 64 + n * 16 + l15] =
            f2bf(acc_o[n][r] * lr);
    }
  };

  stage(0, 0);  // prologue: kt=0 -> buf0

  const int steps = 33;  // (pair+1) + (32-pair)
  for (int s = 0; s < steps; s++) {
    const int kt = (s > pair) ? (s - pair - 1) : s;
    const int d  = s & 1;

    __syncthreads();  // buf d ready (vmcnt drained); all waves done with buf d^1

    if (s + 1 < steps) {
      int kt_n = (s + 1 > pair) ? (s - pair) : (s + 1);
      stage(d ^ 1, kt_n * 64);  // async; completes under this step's compute
    }

    if (s == pair + 1) {  // q-tile switch: flush tile A, reset, swap Q frags
      writeout();
#pragma unroll
      for (int n = 0; n < 4; n++) acc_o[n] = (f32x4){0.f, 0.f, 0.f, 0.f};
      mrun = -1e30f; lrun = 0.f;
      qt = qtB; wq0 = wq0B; qrow = wq0B + l15;
      qf0 = qB0; qf1 = qB1;
    }

    const int k0 = kt * 64;

    // S^T[j]: row (quad*4+r) = k_local, col l15 = q   (swizzled Ks reads)
    f32x4 sacc[4];
#pragma unroll
    for (int j = 0; j < 4; j++) sacc[j] = (f32x4){0.f, 0.f, 0.f, 0.f};
#pragma unroll
    for (int j = 0; j < 4; j++) {
      int krow = j * 16 + l15;
      const char* kb = (const char*)&Ks[d][0] + krow * 128;
      bf16x8 kfa = *(const bf16x8*)(kb + ((quad ^ (krow & 7)) << 4));
      bf16x8 kfb = *(const bf16x8*)(kb + (((4 + quad) ^ (krow & 7)) << 4));
      sacc[j] = __builtin_amdgcn_mfma_f32_16x16x32_bf16(kfa, qf0, sacc[j], 0, 0, 0);
      sacc[j] = __builtin_amdgcn_mfma_f32_16x16x32_bf16(kfb, qf1, sacc[j], 0, 0, 0);
    }

    if (kt == qt) {
#pragma unroll
      for (int j = 0; j < 4; j++)
#pragma unroll
        for (int r = 0; r < 4; r++) {
          int k = k0 + j * 16 + quad * 4 + r;
          sacc[j][r] = (k > qrow) ? -1e30f : sacc[j][r] * 0.125f;
        }
    } else {
#pragma unroll
      for (int j = 0; j < 4; j++)
#pragma unroll
        for (int r = 0; r < 4; r++) sacc[j][r] *= 0.125f;
    }

    // online softmax: 15 lane-local max + 2 shfl; same for sum
    float mx = sacc[0][0];
#pragma unroll
    for (int j = 0; j < 4; j++)
#pragma unroll
      for (int r = 0; r < 4; r++) mx = fmaxf(mx, sacc[j][r]);
    mx = fmaxf(mx, __shfl_xor(mx, 16));
    mx = fmaxf(mx, __shfl_xor(mx, 32));
    const float mnew  = fmaxf(mrun, mx);
    const float alpha = __expf(mrun - mnew);
    float sum = 0.f;
#pragma unroll
    for (int j = 0; j < 4; j++)
#pragma unroll
      for (int r = 0; r < 4; r++) {
        float p = __expf(sacc[j][r] - mnew);
        sacc[j][r] = p;
        sum += p;
      }
    sum += __shfl_xor(sum, 16);
    sum += __shfl_xor(sum, 32);
    lrun = lrun * alpha + sum;
    mrun = mnew;

    // rescale O rows: alpha for output row r lives at lane l15 = quad*4+r
#pragma unroll
    for (int r = 0; r < 4; r++) {
      float ar = __shfl(alpha, quad * 4 + r);
#pragma unroll
      for (int n = 0; n < 4; n++) acc_o[n][r] *= ar;
    }

    // P -> bf16 A-frags (m=l15 -> q, k = quad*4+e), in-register
    s4 pa[4];
#pragma unroll
    for (int j = 0; j < 4; j++) pa[j] = cvt4(sacc[j]);

    // PV: B-frag = V^T[d = n*16+l15][k0 + j*16+quad*4 ..+3], swizzled b64 read
#pragma unroll
    for (int j = 0; j < 4; j++)
#pragma unroll
      for (int n = 0; n < 4; n++) {
        int vrow = n * 16 + l15;
        int ch = (j * 2 + (quad >> 1)) ^ (vrow & 7);
        const s4 vf = *(const s4*)((const char*)&Vts[d][0] + vrow * 128 +
                                   (ch << 4) + ((quad & 1) << 3));
        acc_o[n] = mfma16(pa[j], vf, acc_o[n]);
      }
  }

  writeout();  // flush q-tile B
}

extern "C" void kernel_launch(void* const* d_in, const int* in_sizes, int n_in,
                              void* d_out, int out_size, void* d_ws, size_t ws_size,
                              hipStream_t stream) {
  const float* x     = (const float*)d_in[0];   // (2,2048,1024) fp32
  const float* w_qkv = (const float*)d_in[1];   // (3072,1024)   fp32
  const float* w_o   = (const float*)d_in[2];   // (1024,1024)   fp32
  float* out  = (float*)d_out;                  // fp32 (4096,1024)
  float* outk = out + (size_t)4194304;
  float* outv = out + (size_t)8388608;

  u16* qkv = (u16*)d_ws;                        // 4096*3072
  u16* vt  = qkv + (size_t)4096 * 3072;         // 32*64*2048
  u16* ao  = vt  + (size_t)4194304;             // 4096*1024
  u16* xb  = ao  + (size_t)4194304;             // 4096*1024
  u16* wqb = xb  + (size_t)4194304;             // 3072*1024
  u16* wob = wqb + (size_t)3145728;             // 1024*1024

  // 0. fused fp32 -> bf16 conversion (xb, wqb, wob contiguous)
  cvt_all<<<4096, 256, 0, stream>>>(x, w_qkv, w_o, xb);

  // 1. qkv(bf16 ws) = xb @ wqb^T; k/v cols also -> fp32 outputs
  gemm_bt<false, true><<<dim3(24, 32), 256, 0, stream>>>(
      xb, wqb, qkv, outk, outv, 4096, 3072, 1024);
  // 2. v -> v^T ws
  transpose_v<<<dim3(32, 32), 256, 0, stream>>>(qkv, vt);
  // 3. flash attention -> ao (bf16 ws), paired q-tiles, 512 blocks
  attn<<<dim3(16, 32), 256, 0, stream>>>(qkv, vt, ao);
  // 4. out(fp32) = ao @ wob^T  (back to 128x128 tiles)
  gemm_bt<true, false><<<dim3(8, 32), 256, 0, stream>>>(
      ao, wob, out, nullptr, nullptr, 4096, 1024, 1024);
}